// Round 8
// baseline (262.212 us; speedup 1.0000x reference)
//
#include <hip/hip_runtime.h>
#include <stdint.h>

typedef __bf16 bf16x8 __attribute__((ext_vector_type(8)));
typedef float f32x4 __attribute__((ext_vector_type(4)));

#define NSAMPLE 64
static constexpr int Bb = 4, Nn = 16384, Mm = 1024, Cc = 256;
static constexpr int QPB = 8;   // queries per block; grid = 4096/8 = 512

__device__ __forceinline__ unsigned short f2bf(float f) {
  unsigned int u = __builtin_bit_cast(unsigned int, f);
  u = u + 0x7fffu + ((u >> 16) & 1u);
  return (unsigned short)(u >> 16);
}

// async global->LDS, 16B per lane; LDS dest = wave-uniform base + lane*16
__device__ __forceinline__ void gload_lds16(const void* g, void* lds) {
  __builtin_amdgcn_global_load_lds(
      (const __attribute__((address_space(1))) uint32_t*)g,
      (__attribute__((address_space(3))) uint32_t*)lds, 16, 0, 0);
}

// ---------------- weight prep: BN fold; W1 split into feature part (bf16) + coord part (f32) ----
__global__ void prep_kernel(const float* __restrict__ W1, const float* __restrict__ b1,
                            const float* __restrict__ g1, const float* __restrict__ be1,
                            const float* __restrict__ m1, const float* __restrict__ v1,
                            const float* __restrict__ W2, const float* __restrict__ b2,
                            const float* __restrict__ g2, const float* __restrict__ be2,
                            const float* __restrict__ m2, const float* __restrict__ v2,
                            unsigned short* __restrict__ W1b, float* __restrict__ w1c,
                            float* __restrict__ b1e,
                            unsigned short* __restrict__ W2b, float* __restrict__ b2e) {
  int t = blockIdx.x * 256 + threadIdx.x;
  if (t < 256 * 256) {
    int o = t >> 8, k = t & 255;
    float s1 = g1[o] / sqrtf(v1[o] + 1e-5f);
    W1b[t] = f2bf(W1[o * 259 + 3 + k] * s1);   // feature cols 3..258 -> k 0..255
    float s2 = g2[o] / sqrtf(v2[o] + 1e-5f);
    W2b[t] = f2bf(W2[t] * s2);
  }
  if (t < 256 * 3) {
    int o = t / 3, c = t - o * 3;
    float s = g1[o] / sqrtf(v1[o] + 1e-5f);
    w1c[t] = W1[o * 259 + c] * s;              // coord cols 0..2, kept f32
  }
  if (t < 256) {
    float s1 = g1[t] / sqrtf(v1[t] + 1e-5f);
    b1e[t] = s1 * (b1[t] - m1[t]) + be1[t];
    float s2 = g2[t] / sqrtf(v2[t] + 1e-5f);
    b2e[t] = s2 * (b2[t] - m2[t]) + be2[t];
  }
}

// ---------------- xyz -> float4 (x,y,z,|p|^2) — R1 verbatim ----------------
__global__ void xyzw_kernel(const float* __restrict__ xyz, float4* __restrict__ xyzw) {
  int t = blockIdx.x * 256 + threadIdx.x;
  float x = xyz[t * 3], y = xyz[t * 3 + 1], z = xyz[t * 3 + 2];
  float pp = __fadd_rn(__fadd_rn(__fmul_rn(x, x), __fmul_rn(y, y)), __fmul_rn(z, z));
  xyzw[t] = make_float4(x, y, z, pp);
}

// ---------------- feats [B,C,N] f32 -> featsT [B,N,C] bf16; ushort4 writes ----------------
__global__ void featsT_kernel(const float* __restrict__ feats, unsigned short* __restrict__ featsT) {
  __shared__ float tile[64][65];
  int bx = blockIdx.x;            // 4*256*4 = 4096
  int b = bx >> 10;
  int rem = bx & 1023;
  int nt = rem >> 2, ct = rem & 3;
  int t = threadIdx.x, tx = t & 63, ty = t >> 6;
  const float* src = feats + ((size_t)b * Cc + ct * 64) * Nn + nt * 64;
#pragma unroll
  for (int i = 0; i < 16; i++) {
    int c = i * 4 + ty;
    tile[c][tx] = src[(size_t)c * Nn + tx];
  }
  __syncthreads();
  unsigned short* dst = featsT + ((size_t)b * Nn + nt * 64) * Cc + ct * 64;
  int c4 = (t & 15) * 4, n0 = t >> 4;
#pragma unroll
  for (int i = 0; i < 4; i++) {
    int n = i * 16 + n0;
    ushort4 v;
    v.x = f2bf(tile[c4][n]);
    v.y = f2bf(tile[c4 + 1][n]);
    v.z = f2bf(tile[c4 + 2][n]);
    v.w = f2bf(tile[c4 + 3][n]);
    *(ushort4*)&dst[(size_t)n * Cc + c4] = v;
  }
}

// ---------------- ball query — R1 verbatim ----------------
__global__ void ballq_kernel(const float4* __restrict__ xyzw, const float* __restrict__ new_xyz,
                             int* __restrict__ idx) {
  const float r2 = (float)(0.08 * 0.08);
  int bm = blockIdx.x * 4 + (threadIdx.x >> 6);
  int lane = threadIdx.x & 63;
  int b = bm >> 10;
  float qx = new_xyz[bm * 3], qy = new_xyz[bm * 3 + 1], qz = new_xyz[bm * 3 + 2];
  float qq = __fadd_rn(__fadd_rn(__fmul_rn(qx, qx), __fmul_rn(qy, qy)), __fmul_rn(qz, qz));
  const float4* P = xyzw + (size_t)b * Nn;
  int* out = idx + (size_t)bm * NSAMPLE;
  int cnt = 0, first = 0;
  bool havef = false;
  for (int n0 = 0; n0 < Nn; n0 += 64) {
    float4 p = P[n0 + lane];
    float dt = __fadd_rn(__fadd_rn(__fmul_rn(qx, p.x), __fmul_rn(qy, p.y)), __fmul_rn(qz, p.z));
    float d2 = __fsub_rn(__fadd_rn(qq, p.w), __fmul_rn(2.f, dt));
    bool valid = d2 < r2;
    unsigned long long mask = __ballot(valid);
    if (mask) {
      if (!havef) { first = n0 + __builtin_ctzll(mask); havef = true; }
      if (valid) {
        int pos = cnt + __popcll(mask & ((1ull << lane) - 1ull));
        if (pos < NSAMPLE) out[pos] = n0 + lane;
      }
      cnt += (int)__popcll(mask);
      if (cnt >= NSAMPLE) break;
    }
  }
  int cc = cnt < NSAMPLE ? cnt : NSAMPLE;
  if (lane >= cc) out[lane] = havef ? first : 0;
}

// ---------------- fused: gload_lds double-buffered gather, XOR-swizzled LDS, QPB=8 ----------------
// LDS maps: Xf[buf][64][256] bf16 linear; element (r, chunk c of 8 u16) lives at chunk c^(r&7)
// (swizzle applied on the GLOBAL source chunk at gather time and on every LDS read/write — rule #21).
// H(q) aliases Xf[q&1] (the buffer L1(q) just consumed); gather(q+1) fills Xf[(q+1)&1].
// Barriers: B3 __syncthreads (post-L1 reads); B4 raw lgkmcnt(0)+s_barrier (H ready; gather vmcnt
// stays in flight); B5 __syncthreads (drains gather vmcnt before L1(q+1)).
__global__ __launch_bounds__(256) void fused_kernel(
    const unsigned short* __restrict__ featsT, const float4* __restrict__ xyzw,
    const float* __restrict__ new_xyz, const int* __restrict__ idx,
    const unsigned short* __restrict__ W1b, const float* __restrict__ w1c,
    const float* __restrict__ b1e,
    const unsigned short* __restrict__ W2b, const float* __restrict__ b2e,
    float* __restrict__ out) {
  __shared__ unsigned short Xf[2][64 * 256];  // 2 x 32 KB
  __shared__ float Xc[2][4][64];              // rel coords, c-major (conflict-free bcast reads)
  int t = threadIdx.x;
  int wave = t >> 6, lane = t & 63;
  int lr = lane & 15, kg = lane >> 4;
  int wcol = wave * 64;
  int bm0 = blockIdx.x * QPB;
  int b = bm0 >> 10;  // QPB | 1024: block never crosses batches

  float bb1[4], bb2[4], wcx[4], wcy[4], wcz[4];
#pragma unroll
  for (int ni = 0; ni < 4; ni++) {
    int o = wcol + ni * 16 + lr;
    bb1[ni] = b1e[o];
    bb2[ni] = b2e[o];
    wcx[ni] = w1c[o * 3];
    wcy[ni] = w1c[o * 3 + 1];
    wcz[ni] = w1c[o * 3 + 2];
  }

  // ---- prologue: coords + gather for q0 into buf 0 (latency exposed once) ----
  if (t < 64) {
    int ci = idx[(size_t)bm0 * NSAMPLE + t];
    float4 p = xyzw[(size_t)b * Nn + ci];
    float qx = new_xyz[bm0 * 3], qy = new_xyz[bm0 * 3 + 1], qz = new_xyz[bm0 * 3 + 2];
    Xc[0][0][t] = p.x - qx;
    Xc[0][1][t] = p.y - qy;
    Xc[0][2][t] = p.z - qz;
  }
  {
    int idxr = idx[(size_t)bm0 * NSAMPLE + wave * 16 + (lane & 15)];
#pragma unroll
    for (int i = 0; i < 8; i++) {
      int j = wave * 8 + i;                       // covers rows 2j, 2j+1
      int iv = __shfl(idxr, 2 * i + (lane >> 5));
      int r7 = (2 * j + (lane >> 5)) & 7;
      int cg = (lane & 31) ^ r7;                  // swizzled global chunk
      gload_lds16(featsT + ((size_t)b * Nn + iv) * Cc + cg * 8, &Xf[0][j * 512]);
    }
  }
  __syncthreads();

  for (int q = 0; q < QPB; q++) {
    int cur = q & 1, nxt = cur ^ 1;
    int bm = bm0 + q, bm1 = bm + 1;
    bool vn = (q + 1 < QPB);
    int idxr_n = 0, cidx_n = 0;
    if (vn) {
      idxr_n = idx[(size_t)bm1 * NSAMPLE + wave * 16 + (lane & 15)];
      if (t < 64) cidx_n = idx[(size_t)bm1 * NSAMPLE + t];
    }

    // ---- layer 1: feat part [64x256]x[256x256], swizzled LDS reads ----
    f32x4 acc[4][4];
#pragma unroll
    for (int mi = 0; mi < 4; mi++)
#pragma unroll
      for (int ni = 0; ni < 4; ni++) acc[mi][ni] = (f32x4){0.f, 0.f, 0.f, 0.f};
#pragma unroll
    for (int kk = 0; kk < 8; kk++) {
      bf16x8 w[4];
#pragma unroll
      for (int ni = 0; ni < 4; ni++)
        w[ni] = *(const bf16x8*)&W1b[(size_t)(wcol + ni * 16 + lr) * 256 + kk * 32 + kg * 8];
#pragma unroll
      for (int mi = 0; mi < 4; mi++) {
        int r = mi * 16 + lr;
        int cs = ((kk * 4 + kg) ^ (r & 7)) * 8;
        bf16x8 a = *(const bf16x8*)&Xf[cur][r * 256 + cs];
#pragma unroll
        for (int ni = 0; ni < 4; ni++)
          acc[mi][ni] = __builtin_amdgcn_mfma_f32_16x16x32_bf16(a, w[ni], acc[mi][ni], 0, 0, 0);
      }
    }
    __syncthreads();  // B3: all waves done reading Xf[cur]

    // issue next query's gather (zero-VGPR async) + coord loads; overlaps epi1+L2
    float4 pn = make_float4(0.f, 0.f, 0.f, 0.f);
    float qnx = 0.f, qny = 0.f, qnz = 0.f;
    if (vn) {
#pragma unroll
      for (int i = 0; i < 8; i++) {
        int j = wave * 8 + i;
        int iv = __shfl(idxr_n, 2 * i + (lane >> 5));
        int r7 = (2 * j + (lane >> 5)) & 7;
        int cg = (lane & 31) ^ r7;
        gload_lds16(featsT + ((size_t)b * Nn + iv) * Cc + cg * 8, &Xf[nxt][j * 512]);
      }
      if (t < 64) {
        pn = xyzw[(size_t)b * Nn + cidx_n];
        qnx = new_xyz[bm1 * 3]; qny = new_xyz[bm1 * 3 + 1]; qnz = new_xyz[bm1 * 3 + 2];
      }
    }

    // epilogue 1: acc + bias + f32 coord GEMM, relu, bf16 -> H (aliases Xf[cur], swizzled)
#pragma unroll
    for (int mi = 0; mi < 4; mi++)
#pragma unroll
      for (int ni = 0; ni < 4; ni++)
#pragma unroll
        for (int j = 0; j < 4; j++) {
          int r = mi * 16 + kg * 4 + j;
          float h = acc[mi][ni][j] + bb1[ni]
                  + Xc[cur][0][r] * wcx[ni] + Xc[cur][1][r] * wcy[ni] + Xc[cur][2][r] * wcz[ni];
          h = fmaxf(h, 0.f);
          int o = wcol + ni * 16 + lr;
          Xf[cur][r * 256 + ((((o >> 3) ^ (r & 7)) << 3) + (o & 7))] = f2bf(h);
        }
    // B4: order H writes vs H reads across waves WITHOUT draining vmcnt (gather stays in flight)
    asm volatile("s_waitcnt lgkmcnt(0)\n\ts_barrier" ::: "memory");

    // ---- layer 2: [64x256]x[256x256] from H (same swizzle) ----
#pragma unroll
    for (int mi = 0; mi < 4; mi++)
#pragma unroll
      for (int ni = 0; ni < 4; ni++) acc[mi][ni] = (f32x4){0.f, 0.f, 0.f, 0.f};
#pragma unroll
    for (int kk = 0; kk < 8; kk++) {
      bf16x8 w[4];
#pragma unroll
      for (int ni = 0; ni < 4; ni++)
        w[ni] = *(const bf16x8*)&W2b[(size_t)(wcol + ni * 16 + lr) * 256 + kk * 32 + kg * 8];
#pragma unroll
      for (int mi = 0; mi < 4; mi++) {
        int r = mi * 16 + lr;
        int cs = ((kk * 4 + kg) ^ (r & 7)) * 8;
        bf16x8 a = *(const bf16x8*)&Xf[cur][r * 256 + cs];
#pragma unroll
        for (int ni = 0; ni < 4; ni++)
          acc[mi][ni] = __builtin_amdgcn_mfma_f32_16x16x32_bf16(a, w[ni], acc[mi][ni], 0, 0, 0);
      }
    }
    // epilogue 2: bias + relu + max over 64 samples -> out[b][o][m]
    {
      int m = bm & (Mm - 1);
#pragma unroll
      for (int ni = 0; ni < 4; ni++) {
        float v = 0.f;  // relu(max) == max(relu)
#pragma unroll
        for (int mi = 0; mi < 4; mi++)
#pragma unroll
          for (int j = 0; j < 4; j++) v = fmaxf(v, acc[mi][ni][j] + bb2[ni]);
        v = fmaxf(v, __shfl_xor(v, 16));
        v = fmaxf(v, __shfl_xor(v, 32));
        if (kg == 0)
          out[((size_t)b * 256 + wcol + ni * 16 + lr) * Mm + m] = v;
      }
    }
    // stage next query's coords (pn arrived during L2)
    if (vn && t < 64) {
      Xc[nxt][0][t] = pn.x - qnx;
      Xc[nxt][1][t] = pn.y - qny;
      Xc[nxt][2][t] = pn.z - qnz;
    }
    __syncthreads();  // B5: drains gather vmcnt; Xf[nxt] + Xc[nxt] ready for L1(q+1)
  }
}

extern "C" void kernel_launch(void* const* d_in, const int* in_sizes, int n_in,
                              void* d_out, int out_size, void* d_ws, size_t ws_size,
                              hipStream_t stream) {
  (void)in_sizes; (void)n_in; (void)out_size; (void)ws_size;
  const float* xyz     = (const float*)d_in[0];
  const float* new_xyz = (const float*)d_in[1];
  const float* feats   = (const float*)d_in[2];
  const float* W1 = (const float*)d_in[3];
  const float* b1 = (const float*)d_in[4];
  const float* g1 = (const float*)d_in[5];
  const float* be1 = (const float*)d_in[6];
  const float* m1 = (const float*)d_in[7];
  const float* v1 = (const float*)d_in[8];
  const float* W2 = (const float*)d_in[9];
  const float* b2 = (const float*)d_in[10];
  const float* g2 = (const float*)d_in[11];
  const float* be2 = (const float*)d_in[12];
  const float* m2 = (const float*)d_in[13];
  const float* v2 = (const float*)d_in[14];
  float* out = (float*)d_out;

  char* ws = (char*)d_ws;
  unsigned short* W1b   = (unsigned short*)(ws + 0);         // 131072 B
  unsigned short* W2b   = (unsigned short*)(ws + 131072);    // 131072 B
  float*          w1c   = (float*)(ws + 262144);             // 3072 B
  float*          b1e   = (float*)(ws + 265216);             // 1024 B
  float*          b2e   = (float*)(ws + 266240);             // 1024 B
  float4*         xyzw  = (float4*)(ws + 267264);            // 1048576 B
  unsigned short* featsT= (unsigned short*)(ws + 1315840);   // 33554432 B
  int*            idx   = (int*)(ws + 34870272);             // 1048576 B (end ~35.9 MB)

  prep_kernel<<<256, 256, 0, stream>>>(
      W1, b1, g1, be1, m1, v1, W2, b2, g2, be2, m2, v2, W1b, w1c, b1e, W2b, b2e);
  xyzw_kernel<<<(Bb * Nn) / 256, 256, 0, stream>>>(xyz, xyzw);
  featsT_kernel<<<Bb * (Nn / 64) * (Cc / 64), 256, 0, stream>>>(feats, featsT);
  ballq_kernel<<<(Bb * Mm) / 4, 256, 0, stream>>>(xyzw, new_xyz, idx);
  fused_kernel<<<(Bb * Mm) / QPB, 256, 0, stream>>>(featsT, xyzw, new_xyz, idx,
                                                    W1b, w1c, b1e, W2b, b2e, out);
}